// Round 4
// baseline (279.396 us; speedup 1.0000x reference)
//
#include <hip/hip_runtime.h>
#include <hip/hip_bf16.h>

// BERT self-attention. B=2, S=2048, H=1024, NH=16, HD=64.
// Premises (measured): inputs FP32, output FP32, ws >= 24 MB, mask/bias
// zeros (handled generally), tiny launches unsafe -> all grids big.
// Round 15:
//  - attn: 8 waves / 128 qrows per block (grid 16x32). Same per-wave inner
//    loop; K/V tile amortized over 2x output -> L2/L3 staging traffic
//    halves (512->256 MB). Theory: stage-2 is cache-BW bound (~5.5 TB/s
//    observed), not latency bound.
//  - gemm: BK 32->64 (16 K-iterations, half the barriers/vmcnt drains);
//    __launch_bounds__(256,3) to hold 3 blocks/CU.
// Scratch: [0,24M): 96 bf16 planes (q:0-31, k:32-63, vT:64-95), SD each.
//          [24M,32M): X bf16. [32M,38M): W^T bf16 [z][n][k]. (big path)

#define SEQ   2048
#define HID   1024
#define NHEAD 16
#define HD    64
#define SD    ((size_t)SEQ * HD)   // 131072

typedef __bf16 bf16x8 __attribute__((ext_vector_type(8)));
typedef float  f32x4  __attribute__((ext_vector_type(4)));

#define L2E 1.4426950408889634f
#define SOFT_OFF 16.0f   // fixed exp2-domain shift; |s2|<=~11 for this data

__device__ __forceinline__ unsigned short f2b(float f) {
    unsigned int x = __float_as_uint(f);
    x += 0x7FFFu + ((x >> 16) & 1u);   // RTNE
    return (unsigned short)(x >> 16);
}

// ---------------- pre-convert kernels (big-ws path) ----------------
__global__ __launch_bounds__(256) void cvt_x_k(const float* __restrict__ X,
                                               unsigned short* __restrict__ Xb)
{
    const size_t i = ((size_t)blockIdx.x * 256 + threadIdx.x) * 4;
    const float4 v = *(const float4*)(X + i);
    ushort4 o;
    o.x = f2b(v.x); o.y = f2b(v.y); o.z = f2b(v.z); o.w = f2b(v.w);
    *(ushort4*)(Xb + i) = o;
}

// transpose+convert one 64x64 tile of W[k][n] -> Wtb[z][n][k]
__global__ __launch_bounds__(256) void cvt_w_k(
    const float* __restrict__ Wq, const float* __restrict__ Wk,
    const float* __restrict__ Wv, unsigned short* __restrict__ Wtb)
{
    __shared__ __align__(16) unsigned short T[64][68];
    const int z = blockIdx.z;
    const float* __restrict__ W = (z == 0) ? Wq : (z == 1) ? Wk : Wv;
    const int k0 = blockIdx.x * 64, n0 = blockIdx.y * 64;
    const int tid = threadIdx.x;
    #pragma unroll
    for (int it = 0; it < 16; ++it) {
        const int idx = 256 * it + tid;
        const int r = idx >> 6, c = idx & 63;
        T[c][r] = f2b(W[(size_t)(k0 + r) * HID + n0 + c]);
    }
    __syncthreads();
    unsigned short* dst = Wtb + (size_t)z * HID * HID;
    #pragma unroll
    for (int it = 0; it < 4; ++it) {
        const int idx = 256 * it + tid;
        const int n = idx >> 4, c4 = (idx & 15) * 4;
        *(ushort4*)(dst + (size_t)(n0 + n) * HID + k0 + c4) = *(ushort4*)&T[n][c4];
    }
}

// ---------------- shared GEMM epilogue (LDS-staged, coalesced) ----------
// Et = this wave's [32][68] LDS region (aliases the staging pool).
// Two 32-row halves; 8B ushort4 stores into 128-256B contiguous segments.
__device__ __forceinline__ void gemm_epilogue(
    f32x4 acc[4][4], const float* __restrict__ Bp,
    unsigned short* __restrict__ scratch, unsigned short (*Et)[68],
    int z, int m0, int n0, int wr, int wc, int ln, int quad)
{
    const int b = m0 >> 11;
    const int srow0 = (m0 + wr) & (SEQ - 1);
    const int head = (n0 + wc) >> 6;
    __syncthreads();   // all waves done with Xs/Wt (Et aliases them)

    if (z == 2) {      // V plane transposed: [d][s]; halves over dim (nt)
        #pragma unroll
        for (int half = 0; half < 2; ++half) {
            #pragma unroll
            for (int nt2 = 0; nt2 < 2; ++nt2) {
                const int nt = half * 2 + nt2;
                const float bias = Bp[n0 + wc + nt * 16 + ln];
                #pragma unroll
                for (int mt = 0; mt < 4; ++mt) {
                    ushort4 o;
                    o.x = f2b(acc[mt][nt][0] + bias);
                    o.y = f2b(acc[mt][nt][1] + bias);
                    o.z = f2b(acc[mt][nt][2] + bias);
                    o.w = f2b(acc[mt][nt][3] + bias);
                    *(ushort4*)&Et[nt2 * 16 + ln][mt * 16 + quad * 4] = o;
                }
            }
            __syncthreads();
            #pragma unroll
            for (int it = 0; it < 8; ++it) {
                const int d = it * 4 + quad, s4 = ln * 4;
                *(ushort4*)(scratch +
                    ((size_t)(64 + b * NHEAD + head) * HD + half * 32 + d) * SEQ
                    + srow0 + s4) = *(const ushort4*)&Et[d][s4];
            }
            __syncthreads();
        }
    } else {           // q/k planes [s][d]; halves over srow (mt)
        #pragma unroll
        for (int half = 0; half < 2; ++half) {
            #pragma unroll
            for (int mt2 = 0; mt2 < 2; ++mt2) {
                const int mt = half * 2 + mt2;
                #pragma unroll
                for (int nt = 0; nt < 4; ++nt) {
                    const float bias = Bp[n0 + wc + nt * 16 + ln];
                    #pragma unroll
                    for (int r = 0; r < 4; ++r)
                        Et[mt2 * 16 + quad * 4 + r][nt * 16 + ln] =
                            f2b(acc[mt][nt][r] + bias);
                }
            }
            __syncthreads();
            #pragma unroll
            for (int it = 0; it < 8; ++it) {
                const int r = it * 4 + quad, c4 = ln * 4;
                *(ushort4*)(scratch +
                    ((size_t)(z * 32 + b * NHEAD + head) * SEQ + srow0
                     + half * 32 + r) * HD + c4) = *(const ushort4*)&Et[r][c4];
            }
            __syncthreads();
        }
    }
}

// ---------------- Stage 1a: GEMM from pre-converted bf16, BK=64 ---------
__global__ __launch_bounds__(256, 3) void qkv_gemm_bf16(
    const unsigned short* __restrict__ Xb, const unsigned short* __restrict__ Wtb,
    const float* __restrict__ bq, const float* __restrict__ bk,
    const float* __restrict__ bv, unsigned short* __restrict__ scratch)
{
    __shared__ __align__(16) unsigned char pool[36864];
    unsigned short (*Xs)[72] = (unsigned short (*)[72])pool;            // 18432
    unsigned short (*Wt)[72] = (unsigned short (*)[72])(pool + 18432);  // 18432

    const int z = blockIdx.z;
    const float* __restrict__ Bp = (z == 0) ? bq : (z == 1) ? bk : bv;
    const unsigned short* __restrict__ Wz = Wtb + (size_t)z * HID * HID;

    const int tid = threadIdx.x, w = tid >> 6, lane = tid & 63;
    const int ln = lane & 15, quad = lane >> 4;
    const int wr = (w >> 1) * 64, wc = (w & 1) * 64;
    const int m0 = blockIdx.x * 128, n0 = blockIdx.y * 128;
    const int sr = tid >> 3, c8 = (tid & 7) * 8;   // 32 rows x 64 cols per it

    f32x4 acc[4][4];
    #pragma unroll
    for (int i = 0; i < 4; ++i)
        #pragma unroll
        for (int j = 0; j < 4; ++j) acc[i][j] = (f32x4){0.f, 0.f, 0.f, 0.f};

    // reg-staged pipeline: prologue loads for k0 = 0
    uint4 xg[4], wg[4];
    #pragma unroll
    for (int it = 0; it < 4; ++it) {
        xg[it] = *(const uint4*)(Xb + (size_t)(m0 + sr + 32 * it) * HID + c8);
        wg[it] = *(const uint4*)(Wz + (size_t)(n0 + sr + 32 * it) * HID + c8);
    }

    for (int k0 = 0; k0 < HID; k0 += 64) {
        __syncthreads();
        #pragma unroll
        for (int it = 0; it < 4; ++it) {
            *(uint4*)&Xs[sr + 32 * it][c8] = xg[it];
            *(uint4*)&Wt[sr + 32 * it][c8] = wg[it];
        }
        __syncthreads();
        const int kn = (k0 + 64) & (HID - 1);   // wraps to 0 on last iter
        #pragma unroll
        for (int it = 0; it < 4; ++it) {
            xg[it] = *(const uint4*)(Xb + (size_t)(m0 + sr + 32 * it) * HID + kn + c8);
            wg[it] = *(const uint4*)(Wz + (size_t)(n0 + sr + 32 * it) * HID + kn + c8);
        }

        #pragma unroll
        for (int kk = 0; kk < 2; ++kk) {
            bf16x8 am[4], bn[4];
            #pragma unroll
            for (int t = 0; t < 4; ++t) {
                am[t] = *(const bf16x8*)&Xs[wr + t * 16 + ln][kk * 32 + quad * 8];
                bn[t] = *(const bf16x8*)&Wt[wc + t * 16 + ln][kk * 32 + quad * 8];
            }
            #pragma unroll
            for (int mt = 0; mt < 4; ++mt)
                #pragma unroll
                for (int nt = 0; nt < 4; ++nt)
                    acc[mt][nt] = __builtin_amdgcn_mfma_f32_16x16x32_bf16(
                        am[mt], bn[nt], acc[mt][nt], 0, 0, 0);
        }
    }
    unsigned short (*Et)[68] = (unsigned short (*)[68])(pool + (size_t)w * 4352);
    gemm_epilogue(acc, Bp, scratch, Et, z, m0, n0, wr, wc, ln, quad);
}

// ---------------- Stage 1b: GEMM from fp32 (fallback, r14-proven) -------
__global__ __launch_bounds__(256) void qkv_gemm_fp32(
    const float* __restrict__ X,
    const float* __restrict__ Wq, const float* __restrict__ bq,
    const float* __restrict__ Wk, const float* __restrict__ bk,
    const float* __restrict__ Wv, const float* __restrict__ bv,
    unsigned short* __restrict__ scratch)
{
    __shared__ __align__(16) unsigned char pool[20480];
    unsigned short (*Xs)[40] = (unsigned short (*)[40])pool;
    unsigned short (*Wt)[40] = (unsigned short (*)[40])(pool + 10240);

    const int z = blockIdx.z;
    const float* __restrict__ W  = (z == 0) ? Wq : (z == 1) ? Wk : Wv;
    const float* __restrict__ Bp = (z == 0) ? bq : (z == 1) ? bk : bv;

    const int tid = threadIdx.x, w = tid >> 6, lane = tid & 63;
    const int ln = lane & 15, quad = lane >> 4;
    const int wr = (w >> 1) * 64, wc = (w & 1) * 64;
    const int m0 = blockIdx.x * 128, n0 = blockIdx.y * 128;

    const int xr = tid >> 3, xc = (tid & 7) * 4;
    const int wkr = tid >> 5, wnc = (tid & 31) * 4;

    f32x4 acc[4][4];
    #pragma unroll
    for (int i = 0; i < 4; ++i)
        #pragma unroll
        for (int j = 0; j < 4; ++j) acc[i][j] = (f32x4){0.f, 0.f, 0.f, 0.f};

    for (int k0 = 0; k0 < HID; k0 += 32) {
        __syncthreads();
        #pragma unroll
        for (int it = 0; it < 4; ++it) {
            const int r = xr + 32 * it;
            const float4 xv = *(const float4*)(X + (size_t)(m0 + r) * HID + k0 + xc);
            ushort4 xb;
            xb.x = f2b(xv.x); xb.y = f2b(xv.y); xb.z = f2b(xv.z); xb.w = f2b(xv.w);
            *(ushort4*)&Xs[r][xc] = xb;
            const int kr = wkr + 8 * it;
            const float4 wv = *(const float4*)(W + (size_t)(k0 + kr) * HID + n0 + wnc);
            Wt[wnc + 0][kr] = f2b(wv.x);
            Wt[wnc + 1][kr] = f2b(wv.y);
            Wt[wnc + 2][kr] = f2b(wv.z);
            Wt[wnc + 3][kr] = f2b(wv.w);
        }
        __syncthreads();
        bf16x8 am[4], bn[4];
        #pragma unroll
        for (int t = 0; t < 4; ++t) {
            am[t] = *(const bf16x8*)&Xs[wr + t * 16 + ln][quad * 8];
            bn[t] = *(const bf16x8*)&Wt[wc + t * 16 + ln][quad * 8];
        }
        #pragma unroll
        for (int mt = 0; mt < 4; ++mt)
            #pragma unroll
            for (int nt = 0; nt < 4; ++nt)
                acc[mt][nt] = __builtin_amdgcn_mfma_f32_16x16x32_bf16(
                    am[mt], bn[nt], acc[mt][nt], 0, 0, 0);
    }
    unsigned short (*Et)[68] = (unsigned short (*)[68])(pool + (size_t)w * 4352);
    gemm_epilogue(acc, Bp, scratch, Et, z, m0, n0, wr, wc, ln, quad);
}

// ---------------- Stage 2: flash attention, transposed algebra ----------
// S^T[key][qrow] = K.Q^T ; O^T[d][qrow] = V^T.P^T. qrow = lane&15 =>
// per-lane softmax state; all LDS traffic vectorized.
// R15: 8 waves / 128 qrows per block; K/V tile amortized 2x.
__global__ __launch_bounds__(512) void attn_mfma(
    const unsigned short* __restrict__ scratch,
    const float* __restrict__ mask,
    float* __restrict__ out)
{
    __shared__ __align__(16) unsigned char smem[36864];
    unsigned short (*Ks)[72] = (unsigned short (*)[72])smem;            //  9216 B
    unsigned short (*Vt)[72] = (unsigned short (*)[72])(smem + 9216);   //  9216 B
    unsigned short (*Ps)[72] = (unsigned short (*)[72])(smem + 18432);  // 18432 B
    float (*Obuf)[68] = (float (*)[68])smem;                            // 34816 B (aliases all)

    const int qt = blockIdx.x;
    const int bh = blockIdx.y;
    const int b = bh >> 4, head = bh & 15;

    const unsigned short* __restrict__ Qp  = scratch + (size_t)bh * SD;
    const unsigned short* __restrict__ Kp  = scratch + (size_t)(32 + bh) * SD;
    const unsigned short* __restrict__ Vtp = scratch + (size_t)(64 + bh) * SD; // [d][s]
    const float* __restrict__ maskp = mask + b * SEQ;

    const int tid = threadIdx.x, w = tid >> 6, lane = tid & 63;
    const int ln = lane & 15, quad = lane >> 4;

    // Q as B-frags of Q^T: B[k=d][n=qrow] -> lane ln = qrow, quad gives d-chunk
    const int qrow = qt * 128 + w * 16 + ln;
    const bf16x8 qb0 = *(const bf16x8*)(Qp + (size_t)qrow * HD + quad * 8);
    const bf16x8 qb1 = *(const bf16x8*)(Qp + (size_t)qrow * HD + 32 + quad * 8);

    f32x4 O[4];
    #pragma unroll
    for (int t = 0; t < 4; ++t) O[t] = (f32x4){0.f, 0.f, 0.f, 0.f};
    float lr = 0.0f;   // per-lane partial softmax denominator (fixed offset)

    const int sr8 = tid >> 3, sc8 = (tid & 7) * 8;   // 64 rows x 64 cols, 16B

    // prologue: stage tile 0 into regs (one uint4 each for K and V)
    uint4 kg = *(const uint4*)(Kp + (size_t)sr8 * HD + sc8);
    uint4 vg = *(const uint4*)(Vtp + (size_t)sr8 * SEQ + sc8);

    for (int kt = 0; kt < 32; ++kt) {
        __syncthreads();           // all waves done reading tile kt-1
        *(uint4*)&Ks[sr8][sc8] = kg;
        *(uint4*)&Vt[sr8][sc8] = vg;
        __syncthreads();
        const int kn = (kt + 1) & 31;   // wraps to 0 on last iter (harmless)
        kg = *(const uint4*)(Kp + (size_t)(kn * 64 + sr8) * HD + sc8);
        vg = *(const uint4*)(Vtp + (size_t)sr8 * SEQ + kn * 64 + sc8);

        // S^T: A = K rows (m=key), B = Q^T
        f32x4 s[4];
        #pragma unroll
        for (int t = 0; t < 4; ++t) {
            const bf16x8 ka0 = *(const bf16x8*)&Ks[t * 16 + ln][quad * 8];
            const bf16x8 ka1 = *(const bf16x8*)&Ks[t * 16 + ln][32 + quad * 8];
            f32x4 a = (f32x4){0.f, 0.f, 0.f, 0.f};
            a = __builtin_amdgcn_mfma_f32_16x16x32_bf16(ka0, qb0, a, 0, 0, 0);
            a = __builtin_amdgcn_mfma_f32_16x16x32_bf16(ka1, qb1, a, 0, 0, 0);
            s[t] = a;
        }

        // p = exp2(s*0.125*L2E + mask*L2E - OFF); fixed offset -> no max
        // tracking, no O rescale. Pack to bf16 via v_cvt_pk_bf16_f32.
        const float c = 0.125f * L2E;
        #pragma unroll
        for (int t = 0; t < 4; ++t) {
            const float4 mk4 = *(const float4*)(maskp + kt * 64 + t * 16 + quad * 4);
            const float b0 = fmaf(mk4.x, L2E, -SOFT_OFF);
            const float b1 = fmaf(mk4.y, L2E, -SOFT_OFF);
            const float b2 = fmaf(mk4.z, L2E, -SOFT_OFF);
            const float b3 = fmaf(mk4.w, L2E, -SOFT_OFF);
            const float p0 = exp2f(fmaf(s[t][0], c, b0));
            const float p1 = exp2f(fmaf(s[t][1], c, b1));
            const float p2 = exp2f(fmaf(s[t][2], c, b2));
            const float p3 = exp2f(fmaf(s[t][3], c, b3));
            lr += (p0 + p1) + (p2 + p3);
            unsigned int w0, w1;
            asm("v_cvt_pk_bf16_f32 %0, %1, %2" : "=v"(w0) : "v"(p0), "v"(p1));
            asm("v_cvt_pk_bf16_f32 %0, %1, %2" : "=v"(w1) : "v"(p2), "v"(p3));
            uint2 pw; pw.x = w0; pw.y = w1;
            *(uint2*)&Ps[w * 16 + ln][t * 16 + quad * 4] = pw;
        }

        // O^T += V^T . P^T  (Ps rows are wave-local -> no barrier needed)
        const bf16x8 pb0 = *(const bf16x8*)&Ps[w * 16 + ln][quad * 8];
        const bf16x8 pb1 = *(const bf16x8*)&Ps[w * 16 + ln][32 + quad * 8];
        #pragma unroll
        for (int t = 0; t < 4; ++t) {
            const bf16x8 va0 = *(const bf16x8*)&Vt[t * 16 + ln][quad * 8];
            const bf16x8 va1 = *(const bf16x8*)&Vt[t * 16 + ln][32 + quad * 8];
            O[t] = __builtin_amdgcn_mfma_f32_16x16x32_bf16(va0, pb0, O[t], 0, 0, 0);
            O[t] = __builtin_amdgcn_mfma_f32_16x16x32_bf16(va1, pb1, O[t], 0, 0, 0);
        }
    }

    // single cross-quad reduction of the denominator
    lr += __shfl_xor(lr, 16);
    lr += __shfl_xor(lr, 32);

    // epilogue: normalize, transpose via LDS, coalesced float4 out
    __syncthreads();   // done reading Ks/Vt/Ps; Obuf aliases them
    const float inv = 1.0f / lr;
    #pragma unroll
    for (int t = 0; t < 4; ++t) {
        float4 o4;
        o4.x = O[t][0] * inv; o4.y = O[t][1] * inv;
        o4.z = O[t][2] * inv; o4.w = O[t][3] * inv;
        *(float4*)&Obuf[w * 16 + ln][t * 16 + quad * 4] = o4;   // [qrow][d]
    }
    __syncthreads();
    #pragma unroll
    for (int it = 0; it < 4; ++it) {
        const int r = (tid >> 4) + 32 * it, c4 = (tid & 15) * 4;
        *(float4*)(out + ((size_t)b * SEQ + qt * 128 + r) * HID + head * HD + c4)
            = *(const float4*)&Obuf[r][c4];
    }
}

extern "C" void kernel_launch(void* const* d_in, const int* in_sizes, int n_in,
                              void* d_out, int out_size, void* d_ws, size_t ws_size,
                              hipStream_t stream) {
    const float* X    = (const float*)d_in[0];
    const float* mask = (const float*)d_in[1];
    const float* Wq   = (const float*)d_in[2];
    const float* bq   = (const float*)d_in[3];
    const float* Wk   = (const float*)d_in[4];
    const float* bk   = (const float*)d_in[5];
    const float* Wv   = (const float*)d_in[6];
    const float* bv   = (const float*)d_in[7];

    unsigned short* scratch = (unsigned short*)d_ws;   // 24 MB qkv planes
    float* out = (float*)d_out;

    const bool big = (ws_size >= (40ull << 20));
    if (big) {
        unsigned short* Xb  = scratch + 96 * SD;              // +24 MB, 8 MB
        unsigned short* Wtb = Xb + (size_t)2 * SEQ * HID;     // +32 MB, 6 MB
        cvt_x_k<<<4096, 256, 0, stream>>>(X, Xb);
        cvt_w_k<<<dim3(16, 16, 3), 256, 0, stream>>>(Wq, Wk, Wv, Wtb);
        qkv_gemm_bf16<<<dim3(32, 8, 3), 256, 0, stream>>>(
            Xb, Wtb, bq, bk, bv, scratch);
    } else {
        qkv_gemm_fp32<<<dim3(32, 8, 3), 256, 0, stream>>>(
            X, Wq, bq, Wk, bk, Wv, bv, scratch);
    }
    attn_mfma<<<dim3(SEQ / 128, 32), 512, 0, stream>>>(scratch, mask, out);
}

// Round 5
// 214.784 us; speedup vs baseline: 1.3008x; 1.3008x over previous
//
#include <hip/hip_runtime.h>
#include <hip/hip_bf16.h>

// BERT self-attention. B=2, S=2048, H=1024, NH=16, HD=64.
// Premises (measured): inputs FP32, output FP32, ws >= 24 MB, mask/bias
// zeros (handled generally), tiny launches unsafe -> all grids big.
// Round 16:
//  - gemm: full revert to R14 (BK=32, pool 20480) -- BK=64 regressed 40%+
//    with anomalous WRITE_SIZE; R14 form is the proven best.
//  - attn: keep R14 4-wave/64-qrow inner loop, add (a) K/V LDS double
//    buffer -> ONE barrier per kt (staging writes overlap compute),
//    (b) XCD-chunked block swizzle -> 4 bh per XCD -> K/V (2 MB) fits
//    private L2. Targets the measured ~65% stall (vmcnt/lgkm drain at
//    2 barriers/kt + L3-latency loads).
// Scratch: [0,24M): 96 bf16 planes (q:0-31, k:32-63, vT:64-95), SD each.
//          [24M,32M): X bf16. [32M,38M): W^T bf16 [z][n][k]. (big path)

#define SEQ   2048
#define HID   1024
#define NHEAD 16
#define HD    64
#define SD    ((size_t)SEQ * HD)   // 131072

typedef __bf16 bf16x8 __attribute__((ext_vector_type(8)));
typedef float  f32x4  __attribute__((ext_vector_type(4)));

#define L2E 1.4426950408889634f
#define SOFT_OFF 16.0f   // fixed exp2-domain shift; |s2|<=~11 for this data

__device__ __forceinline__ unsigned short f2b(float f) {
    unsigned int x = __float_as_uint(f);
    x += 0x7FFFu + ((x >> 16) & 1u);   // RTNE
    return (unsigned short)(x >> 16);
}

// ---------------- pre-convert kernels (big-ws path) ----------------
__global__ __launch_bounds__(256) void cvt_x_k(const float* __restrict__ X,
                                               unsigned short* __restrict__ Xb)
{
    const size_t i = ((size_t)blockIdx.x * 256 + threadIdx.x) * 4;
    const float4 v = *(const float4*)(X + i);
    ushort4 o;
    o.x = f2b(v.x); o.y = f2b(v.y); o.z = f2b(v.z); o.w = f2b(v.w);
    *(ushort4*)(Xb + i) = o;
}

// transpose+convert one 64x64 tile of W[k][n] -> Wtb[z][n][k]
__global__ __launch_bounds__(256) void cvt_w_k(
    const float* __restrict__ Wq, const float* __restrict__ Wk,
    const float* __restrict__ Wv, unsigned short* __restrict__ Wtb)
{
    __shared__ __align__(16) unsigned short T[64][68];
    const int z = blockIdx.z;
    const float* __restrict__ W = (z == 0) ? Wq : (z == 1) ? Wk : Wv;
    const int k0 = blockIdx.x * 64, n0 = blockIdx.y * 64;
    const int tid = threadIdx.x;
    #pragma unroll
    for (int it = 0; it < 16; ++it) {
        const int idx = 256 * it + tid;
        const int r = idx >> 6, c = idx & 63;
        T[c][r] = f2b(W[(size_t)(k0 + r) * HID + n0 + c]);
    }
    __syncthreads();
    unsigned short* dst = Wtb + (size_t)z * HID * HID;
    #pragma unroll
    for (int it = 0; it < 4; ++it) {
        const int idx = 256 * it + tid;
        const int n = idx >> 4, c4 = (idx & 15) * 4;
        *(ushort4*)(dst + (size_t)(n0 + n) * HID + k0 + c4) = *(ushort4*)&T[n][c4];
    }
}

// ---------------- shared GEMM epilogue (LDS-staged, coalesced) ----------
// Et = this wave's [32][68] LDS region (aliases Xs/Wt pool; caller's pool).
// Two 32-row halves; 8B ushort4 stores into 128-256B contiguous segments.
__device__ __forceinline__ void gemm_epilogue(
    f32x4 acc[4][4], const float* __restrict__ Bp,
    unsigned short* __restrict__ scratch, unsigned short (*Et)[68],
    int z, int m0, int n0, int wr, int wc, int ln, int quad)
{
    const int b = m0 >> 11;
    const int srow0 = (m0 + wr) & (SEQ - 1);
    const int head = (n0 + wc) >> 6;
    __syncthreads();   // all waves done with Xs/Wt (Et aliases them)

    if (z == 2) {      // V plane transposed: [d][s]; halves over dim (nt)
        #pragma unroll
        for (int half = 0; half < 2; ++half) {
            #pragma unroll
            for (int nt2 = 0; nt2 < 2; ++nt2) {
                const int nt = half * 2 + nt2;
                const float bias = Bp[n0 + wc + nt * 16 + ln];
                #pragma unroll
                for (int mt = 0; mt < 4; ++mt) {
                    ushort4 o;
                    o.x = f2b(acc[mt][nt][0] + bias);
                    o.y = f2b(acc[mt][nt][1] + bias);
                    o.z = f2b(acc[mt][nt][2] + bias);
                    o.w = f2b(acc[mt][nt][3] + bias);
                    *(ushort4*)&Et[nt2 * 16 + ln][mt * 16 + quad * 4] = o;
                }
            }
            __syncthreads();
            #pragma unroll
            for (int it = 0; it < 8; ++it) {
                const int d = it * 4 + quad, s4 = ln * 4;
                *(ushort4*)(scratch +
                    ((size_t)(64 + b * NHEAD + head) * HD + half * 32 + d) * SEQ
                    + srow0 + s4) = *(const ushort4*)&Et[d][s4];
            }
            __syncthreads();
        }
    } else {           // q/k planes [s][d]; halves over srow (mt)
        #pragma unroll
        for (int half = 0; half < 2; ++half) {
            #pragma unroll
            for (int mt2 = 0; mt2 < 2; ++mt2) {
                const int mt = half * 2 + mt2;
                #pragma unroll
                for (int nt = 0; nt < 4; ++nt) {
                    const float bias = Bp[n0 + wc + nt * 16 + ln];
                    #pragma unroll
                    for (int r = 0; r < 4; ++r)
                        Et[mt2 * 16 + quad * 4 + r][nt * 16 + ln] =
                            f2b(acc[mt][nt][r] + bias);
                }
            }
            __syncthreads();
            #pragma unroll
            for (int it = 0; it < 8; ++it) {
                const int r = it * 4 + quad, c4 = ln * 4;
                *(ushort4*)(scratch +
                    ((size_t)(z * 32 + b * NHEAD + head) * SEQ + srow0
                     + half * 32 + r) * HD + c4) = *(const ushort4*)&Et[r][c4];
            }
            __syncthreads();
        }
    }
}

// ---------------- Stage 1a: GEMM from pre-converted bf16 (R14) ----------
__global__ __launch_bounds__(256) void qkv_gemm_bf16(
    const unsigned short* __restrict__ Xb, const unsigned short* __restrict__ Wtb,
    const float* __restrict__ bq, const float* __restrict__ bk,
    const float* __restrict__ bv, unsigned short* __restrict__ scratch)
{
    __shared__ __align__(16) unsigned char pool[20480];
    unsigned short (*Xs)[40] = (unsigned short (*)[40])pool;            // 10240
    unsigned short (*Wt)[40] = (unsigned short (*)[40])(pool + 10240);  // 10240

    const int z = blockIdx.z;
    const float* __restrict__ Bp = (z == 0) ? bq : (z == 1) ? bk : bv;
    const unsigned short* __restrict__ Wz = Wtb + (size_t)z * HID * HID;

    const int tid = threadIdx.x, w = tid >> 6, lane = tid & 63;
    const int ln = lane & 15, quad = lane >> 4;
    const int wr = (w >> 1) * 64, wc = (w & 1) * 64;
    const int m0 = blockIdx.x * 128, n0 = blockIdx.y * 128;
    const int sr = tid >> 2, c8 = (tid & 3) * 8;

    f32x4 acc[4][4];
    #pragma unroll
    for (int i = 0; i < 4; ++i)
        #pragma unroll
        for (int j = 0; j < 4; ++j) acc[i][j] = (f32x4){0.f, 0.f, 0.f, 0.f};

    // reg-staged pipeline: prologue loads for k0 = 0
    uint4 xg0 = *(const uint4*)(Xb + (size_t)(m0 + sr) * HID + c8);
    uint4 xg1 = *(const uint4*)(Xb + (size_t)(m0 + sr + 64) * HID + c8);
    uint4 wg0 = *(const uint4*)(Wz + (size_t)(n0 + sr) * HID + c8);
    uint4 wg1 = *(const uint4*)(Wz + (size_t)(n0 + sr + 64) * HID + c8);

    for (int k0 = 0; k0 < HID; k0 += 32) {
        __syncthreads();
        *(uint4*)&Xs[sr][c8]      = xg0;
        *(uint4*)&Xs[sr + 64][c8] = xg1;
        *(uint4*)&Wt[sr][c8]      = wg0;
        *(uint4*)&Wt[sr + 64][c8] = wg1;
        __syncthreads();
        const int kn = (k0 + 32) & (HID - 1);   // wraps to 0 on last iter
        xg0 = *(const uint4*)(Xb + (size_t)(m0 + sr) * HID + kn + c8);
        xg1 = *(const uint4*)(Xb + (size_t)(m0 + sr + 64) * HID + kn + c8);
        wg0 = *(const uint4*)(Wz + (size_t)(n0 + sr) * HID + kn + c8);
        wg1 = *(const uint4*)(Wz + (size_t)(n0 + sr + 64) * HID + kn + c8);

        bf16x8 am[4], bn[4];
        #pragma unroll
        for (int t = 0; t < 4; ++t) {
            am[t] = *(const bf16x8*)&Xs[wr + t * 16 + ln][quad * 8];
            bn[t] = *(const bf16x8*)&Wt[wc + t * 16 + ln][quad * 8];
        }
        #pragma unroll
        for (int mt = 0; mt < 4; ++mt)
            #pragma unroll
            for (int nt = 0; nt < 4; ++nt)
                acc[mt][nt] = __builtin_amdgcn_mfma_f32_16x16x32_bf16(
                    am[mt], bn[nt], acc[mt][nt], 0, 0, 0);
    }
    unsigned short (*Et)[68] = (unsigned short (*)[68])(pool + (size_t)w * 4352);
    gemm_epilogue(acc, Bp, scratch, Et, z, m0, n0, wr, wc, ln, quad);
}

// ---------------- Stage 1b: GEMM from fp32 (fallback, R14) --------------
__global__ __launch_bounds__(256) void qkv_gemm_fp32(
    const float* __restrict__ X,
    const float* __restrict__ Wq, const float* __restrict__ bq,
    const float* __restrict__ Wk, const float* __restrict__ bk,
    const float* __restrict__ Wv, const float* __restrict__ bv,
    unsigned short* __restrict__ scratch)
{
    __shared__ __align__(16) unsigned char pool[20480];
    unsigned short (*Xs)[40] = (unsigned short (*)[40])pool;
    unsigned short (*Wt)[40] = (unsigned short (*)[40])(pool + 10240);

    const int z = blockIdx.z;
    const float* __restrict__ W  = (z == 0) ? Wq : (z == 1) ? Wk : Wv;
    const float* __restrict__ Bp = (z == 0) ? bq : (z == 1) ? bk : bv;

    const int tid = threadIdx.x, w = tid >> 6, lane = tid & 63;
    const int ln = lane & 15, quad = lane >> 4;
    const int wr = (w >> 1) * 64, wc = (w & 1) * 64;
    const int m0 = blockIdx.x * 128, n0 = blockIdx.y * 128;

    const int xr = tid >> 3, xc = (tid & 7) * 4;
    const int wkr = tid >> 5, wnc = (tid & 31) * 4;

    f32x4 acc[4][4];
    #pragma unroll
    for (int i = 0; i < 4; ++i)
        #pragma unroll
        for (int j = 0; j < 4; ++j) acc[i][j] = (f32x4){0.f, 0.f, 0.f, 0.f};

    for (int k0 = 0; k0 < HID; k0 += 32) {
        __syncthreads();
        #pragma unroll
        for (int it = 0; it < 4; ++it) {
            const int r = xr + 32 * it;
            const float4 xv = *(const float4*)(X + (size_t)(m0 + r) * HID + k0 + xc);
            ushort4 xb;
            xb.x = f2b(xv.x); xb.y = f2b(xv.y); xb.z = f2b(xv.z); xb.w = f2b(xv.w);
            *(ushort4*)&Xs[r][xc] = xb;
            const int kr = wkr + 8 * it;
            const float4 wv = *(const float4*)(W + (size_t)(k0 + kr) * HID + n0 + wnc);
            Wt[wnc + 0][kr] = f2b(wv.x);
            Wt[wnc + 1][kr] = f2b(wv.y);
            Wt[wnc + 2][kr] = f2b(wv.z);
            Wt[wnc + 3][kr] = f2b(wv.w);
        }
        __syncthreads();
        bf16x8 am[4], bn[4];
        #pragma unroll
        for (int t = 0; t < 4; ++t) {
            am[t] = *(const bf16x8*)&Xs[wr + t * 16 + ln][quad * 8];
            bn[t] = *(const bf16x8*)&Wt[wc + t * 16 + ln][quad * 8];
        }
        #pragma unroll
        for (int mt = 0; mt < 4; ++mt)
            #pragma unroll
            for (int nt = 0; nt < 4; ++nt)
                acc[mt][nt] = __builtin_amdgcn_mfma_f32_16x16x32_bf16(
                    am[mt], bn[nt], acc[mt][nt], 0, 0, 0);
    }
    unsigned short (*Et)[68] = (unsigned short (*)[68])(pool + (size_t)w * 4352);
    gemm_epilogue(acc, Bp, scratch, Et, z, m0, n0, wr, wc, ln, quad);
}

// ---------------- Stage 2: flash attention, transposed algebra ----------
// S^T[key][qrow] = K.Q^T ; O^T[d][qrow] = V^T.P^T. qrow = lane&15 =>
// per-lane softmax state; all LDS traffic vectorized.
// R16: K/V LDS double-buffer -> ONE barrier per kt; XCD-chunked swizzle
// (4 bh per XCD -> 2 MB K/V working set fits private L2).
__global__ __launch_bounds__(256) void attn_mfma(
    const unsigned short* __restrict__ scratch,
    const float* __restrict__ mask,
    float* __restrict__ out)
{
    __shared__ __align__(16) unsigned char smem[46080];
    unsigned short (*Ks)[64][72] = (unsigned short (*)[64][72])smem;           // 2x9216
    unsigned short (*Vt)[64][72] = (unsigned short (*)[64][72])(smem + 18432); // 2x9216
    unsigned short (*Ps)[72]     = (unsigned short (*)[72])(smem + 36864);     //   9216
    float (*Obuf)[68] = (float (*)[68])smem;    // 17408 B (aliases Ks)

    // XCD-chunked swizzle: nwg=1024, 8 XCDs, 128 blocks/XCD contiguous.
    // XCD x serves wg in [128x,128x+128) -> bh in [4x,4x+4), all 32 qt.
    const int orig = blockIdx.x;
    const int wg = ((orig & 7) << 7) + (orig >> 3);
    const int qt = wg & 31;
    const int bh = wg >> 5;
    const int b = bh >> 4, head = bh & 15;

    const unsigned short* __restrict__ Qp  = scratch + (size_t)bh * SD;
    const unsigned short* __restrict__ Kp  = scratch + (size_t)(32 + bh) * SD;
    const unsigned short* __restrict__ Vtp = scratch + (size_t)(64 + bh) * SD; // [d][s]
    const float* __restrict__ maskp = mask + b * SEQ;

    const int tid = threadIdx.x, w = tid >> 6, lane = tid & 63;
    const int ln = lane & 15, quad = lane >> 4;

    // Q as B-frags of Q^T: B[k=d][n=qrow] -> lane ln = qrow, quad gives d-chunk
    const int qrow = qt * 64 + w * 16 + ln;
    const bf16x8 qb0 = *(const bf16x8*)(Qp + (size_t)qrow * HD + quad * 8);
    const bf16x8 qb1 = *(const bf16x8*)(Qp + (size_t)qrow * HD + 32 + quad * 8);

    f32x4 O[4];
    #pragma unroll
    for (int t = 0; t < 4; ++t) O[t] = (f32x4){0.f, 0.f, 0.f, 0.f};
    float lr = 0.0f;   // per-lane partial softmax denominator (fixed offset)

    const int sr8 = tid >> 3, sc8 = (tid & 7) * 8;   // 16B staging pattern

    // prologue: tile 0 -> buf0; then issue tile-1 loads
    {
        uint4 a = *(const uint4*)(Kp + (size_t)sr8 * HD + sc8);
        uint4 c = *(const uint4*)(Kp + (size_t)(sr8 + 32) * HD + sc8);
        uint4 d = *(const uint4*)(Vtp + (size_t)sr8 * SEQ + sc8);
        uint4 e = *(const uint4*)(Vtp + (size_t)(sr8 + 32) * SEQ + sc8);
        *(uint4*)&Ks[0][sr8][sc8]      = a;
        *(uint4*)&Ks[0][sr8 + 32][sc8] = c;
        *(uint4*)&Vt[0][sr8][sc8]      = d;
        *(uint4*)&Vt[0][sr8 + 32][sc8] = e;
    }
    uint4 kg0 = *(const uint4*)(Kp + (size_t)(64 + sr8) * HD + sc8);
    uint4 kg1 = *(const uint4*)(Kp + (size_t)(64 + sr8 + 32) * HD + sc8);
    uint4 vg0 = *(const uint4*)(Vtp + (size_t)sr8 * SEQ + 64 + sc8);
    uint4 vg1 = *(const uint4*)(Vtp + (size_t)(sr8 + 32) * SEQ + 64 + sc8);
    __syncthreads();

    for (int kt = 0; kt < 32; ++kt) {
        const int cur = kt & 1;
        // stage tile kt+1 into the idle buffer (overlaps compute of cur)
        if (kt < 31) {
            *(uint4*)&Ks[cur ^ 1][sr8][sc8]      = kg0;
            *(uint4*)&Ks[cur ^ 1][sr8 + 32][sc8] = kg1;
            *(uint4*)&Vt[cur ^ 1][sr8][sc8]      = vg0;
            *(uint4*)&Vt[cur ^ 1][sr8 + 32][sc8] = vg1;
        }
        // issue loads for tile kt+2 (drained at this iteration's barrier)
        if (kt < 30) {
            const int kn = kt + 2;
            kg0 = *(const uint4*)(Kp + (size_t)(kn * 64 + sr8) * HD + sc8);
            kg1 = *(const uint4*)(Kp + (size_t)(kn * 64 + sr8 + 32) * HD + sc8);
            vg0 = *(const uint4*)(Vtp + (size_t)sr8 * SEQ + kn * 64 + sc8);
            vg1 = *(const uint4*)(Vtp + (size_t)(sr8 + 32) * SEQ + kn * 64 + sc8);
        }

        // S^T: A = K rows (m=key), B = Q^T
        f32x4 s[4];
        #pragma unroll
        for (int t = 0; t < 4; ++t) {
            const bf16x8 ka0 = *(const bf16x8*)&Ks[cur][t * 16 + ln][quad * 8];
            const bf16x8 ka1 = *(const bf16x8*)&Ks[cur][t * 16 + ln][32 + quad * 8];
            f32x4 a = (f32x4){0.f, 0.f, 0.f, 0.f};
            a = __builtin_amdgcn_mfma_f32_16x16x32_bf16(ka0, qb0, a, 0, 0, 0);
            a = __builtin_amdgcn_mfma_f32_16x16x32_bf16(ka1, qb1, a, 0, 0, 0);
            s[t] = a;
        }

        // p = exp2(s*0.125*L2E + mask*L2E - OFF); fixed offset -> no max
        // tracking, no O rescale. Pack to bf16 via v_cvt_pk_bf16_f32.
        const float c = 0.125f * L2E;
        #pragma unroll
        for (int t = 0; t < 4; ++t) {
            const float4 mk4 = *(const float4*)(maskp + kt * 64 + t * 16 + quad * 4);
            const float b0 = fmaf(mk4.x, L2E, -SOFT_OFF);
            const float b1 = fmaf(mk4.y, L2E, -SOFT_OFF);
            const float b2 = fmaf(mk4.z, L2E, -SOFT_OFF);
            const float b3 = fmaf(mk4.w, L2E, -SOFT_OFF);
            const float p0 = exp2f(fmaf(s[t][0], c, b0));
            const float p1 = exp2f(fmaf(s[t][1], c, b1));
            const float p2 = exp2f(fmaf(s[t][2], c, b2));
            const float p3 = exp2f(fmaf(s[t][3], c, b3));
            lr += (p0 + p1) + (p2 + p3);
            unsigned int w0, w1;
            asm("v_cvt_pk_bf16_f32 %0, %1, %2" : "=v"(w0) : "v"(p0), "v"(p1));
            asm("v_cvt_pk_bf16_f32 %0, %1, %2" : "=v"(w1) : "v"(p2), "v"(p3));
            uint2 pw; pw.x = w0; pw.y = w1;
            *(uint2*)&Ps[w * 16 + ln][t * 16 + quad * 4] = pw;
        }

        // O^T += V^T . P^T  (Ps rows are wave-local -> no barrier needed)
        const bf16x8 pb0 = *(const bf16x8*)&Ps[w * 16 + ln][quad * 8];
        const bf16x8 pb1 = *(const bf16x8*)&Ps[w * 16 + ln][32 + quad * 8];
        #pragma unroll
        for (int t = 0; t < 4; ++t) {
            const bf16x8 va0 = *(const bf16x8*)&Vt[cur][t * 16 + ln][quad * 8];
            const bf16x8 va1 = *(const bf16x8*)&Vt[cur][t * 16 + ln][32 + quad * 8];
            O[t] = __builtin_amdgcn_mfma_f32_16x16x32_bf16(va0, pb0, O[t], 0, 0, 0);
            O[t] = __builtin_amdgcn_mfma_f32_16x16x32_bf16(va1, pb1, O[t], 0, 0, 0);
        }

        __syncthreads();   // single barrier: buf[cur^1] writes visible; all
                           // waves done reading buf[cur] before it's reused
    }

    // single cross-quad reduction of the denominator
    lr += __shfl_xor(lr, 16);
    lr += __shfl_xor(lr, 32);

    // epilogue: normalize, transpose via LDS, coalesced float4 out
    // (loop's final barrier already fenced all Ks/Vt reads; Obuf aliases Ks)
    const float inv = 1.0f / lr;
    #pragma unroll
    for (int t = 0; t < 4; ++t) {
        float4 o4;
        o4.x = O[t][0] * inv; o4.y = O[t][1] * inv;
        o4.z = O[t][2] * inv; o4.w = O[t][3] * inv;
        *(float4*)&Obuf[w * 16 + ln][t * 16 + quad * 4] = o4;   // [qrow][d]
    }
    __syncthreads();
    #pragma unroll
    for (int it = 0; it < 4; ++it) {
        const int r = (tid >> 4) + 16 * it, c4 = (tid & 15) * 4;
        *(float4*)(out + ((size_t)b * SEQ + qt * 64 + r) * HID + head * HD + c4)
            = *(const float4*)&Obuf[r][c4];
    }
}

extern "C" void kernel_launch(void* const* d_in, const int* in_sizes, int n_in,
                              void* d_out, int out_size, void* d_ws, size_t ws_size,
                              hipStream_t stream) {
    const float* X    = (const float*)d_in[0];
    const float* mask = (const float*)d_in[1];
    const float* Wq   = (const float*)d_in[2];
    const float* bq   = (const float*)d_in[3];
    const float* Wk   = (const float*)d_in[4];
    const float* bk   = (const float*)d_in[5];
    const float* Wv   = (const float*)d_in[6];
    const float* bv   = (const float*)d_in[7];

    unsigned short* scratch = (unsigned short*)d_ws;   // 24 MB qkv planes
    float* out = (float*)d_out;

    const bool big = (ws_size >= (40ull << 20));
    if (big) {
        unsigned short* Xb  = scratch + 96 * SD;              // +24 MB, 8 MB
        unsigned short* Wtb = Xb + (size_t)2 * SEQ * HID;     // +32 MB, 6 MB
        cvt_x_k<<<4096, 256, 0, stream>>>(X, Xb);
        cvt_w_k<<<dim3(16, 16, 3), 256, 0, stream>>>(Wq, Wk, Wv, Wtb);
        qkv_gemm_bf16<<<dim3(32, 8, 3), 256, 0, stream>>>(
            Xb, Wtb, bq, bk, bv, scratch);
    } else {
        qkv_gemm_fp32<<<dim3(32, 8, 3), 256, 0, stream>>>(
            X, Wq, bq, Wk, bk, Wv, bv, scratch);
    }
    attn_mfma<<<1024, 256, 0, stream>>>(scratch, mask, out);
}